// Round 1
// baseline (7674.274 us; speedup 1.0000x reference)
//
#include <hip/hip_runtime.h>
#include <math.h>

// Problem constants
#define BB 256   // batch
#define TT 128   // seq len
#define DD 256   // input dim
#define HH 512   // hidden (LSTM 1/2); LSTM 3 hidden = 2*HH = 1024

typedef __bf16 bf16x8 __attribute__((ext_vector_type(8)));
typedef float  f32x4  __attribute__((ext_vector_type(4)));

__device__ inline unsigned short f2bf(float f) {
  unsigned u = __builtin_bit_cast(unsigned, f);
  unsigned r = (u + 0x7fffu + ((u >> 16) & 1u)) >> 16;  // RNE
  return (unsigned short)r;
}
__device__ inline float bf2f(unsigned short h) {
  unsigned u = ((unsigned)h) << 16;
  return __builtin_bit_cast(float, u);
}
__device__ inline float sigm(float x)   { return 1.f / (1.f + __expf(-x)); }
__device__ inline float tanh_f(float x) { return 2.f / (1.f + __expf(-2.f * x)) - 1.f; }
__device__ inline bf16x8 ld8(const unsigned short* p) {
  return *reinterpret_cast<const bf16x8*>(p);
}

// ---------------------------------------------------------------------------
// Prep: convert/pack everything to bf16, gate-interleaved weight layout.
// Packed weight row n = j*4 + g  (g: 0=i,1=f,2=g,3=o), K = [ih | hh] concat.
// xb transposed to [T][B][D] so a step's A-tile is contiguous.
// Zeroes comb slot 0, hs slots, and all c states (ws is poisoned each call).
// ---------------------------------------------------------------------------
__global__ void prep(const float* __restrict__ x,
                     const float* __restrict__ Wf_ih, const float* __restrict__ Wf_hh, const float* __restrict__ bf_,
                     const float* __restrict__ Wb_ih, const float* __restrict__ Wb_hh, const float* __restrict__ bb_,
                     const float* __restrict__ Ws_ih, const float* __restrict__ Ws_hh, const float* __restrict__ bs_,
                     unsigned short* __restrict__ xb, unsigned short* __restrict__ Wpf,
                     unsigned short* __restrict__ Wpb, unsigned short* __restrict__ Wps,
                     float* __restrict__ bpf, float* __restrict__ bpb, float* __restrict__ bps,
                     unsigned short* __restrict__ comb, unsigned short* __restrict__ hs,
                     float* __restrict__ cf, float* __restrict__ cb, float* __restrict__ cs) {
  const long gid = (long)blockIdx.x * blockDim.x + threadIdx.x;
  const long stride = (long)gridDim.x * blockDim.x;

  // x [B][T][D] -> xb [T][B][D] (bf16)
  for (long i = gid; i < (long)BB * TT * DD; i += stride) {
    long k = i % DD;
    long bt = i / DD;
    long t = bt % TT;
    long b = bt / TT;
    xb[(t * BB + b) * DD + k] = f2bf(x[i]);
  }
  // fwd/bwd packed weights: [2048][768]
  for (long i = gid; i < 2048L * 768; i += stride) {
    int n = (int)(i / 768), k = (int)(i - (long)n * 768);
    int j = n >> 2, g = n & 3;
    float vf = (k < DD) ? Wf_ih[(size_t)(g * HH + j) * DD + k]
                        : Wf_hh[(size_t)(g * HH + j) * HH + (k - DD)];
    float vb = (k < DD) ? Wb_ih[(size_t)(g * HH + j) * DD + k]
                        : Wb_hh[(size_t)(g * HH + j) * HH + (k - DD)];
    Wpf[i] = f2bf(vf);
    Wpb[i] = f2bf(vb);
  }
  // layer-3 packed weights: [4096][2048]
  for (long i = gid; i < 4096L * 2048; i += stride) {
    int n = (int)(i >> 11), k = (int)(i & 2047);
    int j = n >> 2, g = n & 3;
    float v = (k < 1024) ? Ws_ih[(size_t)(g * 1024 + j) * 1024 + k]
                         : Ws_hh[(size_t)(g * 1024 + j) * 1024 + (k - 1024)];
    Wps[i] = f2bf(v);
  }
  // biases (fp32, gate-interleaved)
  for (long i = gid; i < 2048; i += stride) {
    int j = (int)(i >> 2), g = (int)(i & 3);
    bpf[i] = bf_[g * HH + j];
    bpb[i] = bb_[g * HH + j];
  }
  for (long i = gid; i < 4096; i += stride) {
    int j = (int)(i >> 2), g = (int)(i & 3);
    bps[i] = bs_[g * 1024 + j];
  }
  // zero init: comb slot 0 (h_{-1} = 0), hs (both slots), c states
  for (long i = gid; i < (long)BB * 1024; i += stride) comb[i] = 0;
  for (long i = gid; i < 2L * BB * 1024; i += stride) hs[i] = 0;
  for (long i = gid; i < (long)BB * HH; i += stride) { cf[i] = 0.f; cb[i] = 0.f; }
  for (long i = gid; i < (long)BB * 1024; i += stride) cs[i] = 0.f;
}

// ---------------------------------------------------------------------------
// One time step of fwd (blocks 0..127) + bwd (blocks 128..255) LSTM.
// gates[256 x 2048] = [x_t | h_{t-1}] @ Wpackedᵀ  (K = 768), 64x64 tiles.
// A frag: A[m=lane&15][k=(lane>>4)*8+j]; B frag: W[n=lane&15][k=...].
// C/D frag: col=lane&15, row=(lane>>4)*4+reg.
// Epilogue: regs -> LDS -> regrouped cell update -> h(bf16) into comb slot t+1.
// ---------------------------------------------------------------------------
__global__ __launch_bounds__(256) void step_fb(int t,
    const unsigned short* __restrict__ xb,
    const unsigned short* __restrict__ Wpf, const unsigned short* __restrict__ Wpb,
    const float* __restrict__ bpf, const float* __restrict__ bpb,
    unsigned short* __restrict__ comb, float* __restrict__ cf, float* __restrict__ cb) {
  __shared__ float lds[64 * 68];
  const int bi = blockIdx.x;
  const int dir = bi >> 7;
  const int rr0 = bi & 127;
  const int m0 = (rr0 >> 5) * 64;   // batch tile
  const int n0 = (rr0 & 31) * 64;   // gate-col tile
  const unsigned short* __restrict__ W = dir ? Wpb : Wpf;
  const float* __restrict__ bias = dir ? bpb : bpf;
  float* __restrict__ cbuf = dir ? cb : cf;
  const int dofs = dir ? HH : 0;
  const int tx = dir ? (TT - 1 - t) : t;

  const int tid = threadIdx.x;
  const int w = tid >> 6;
  const int lane = tid & 63;
  const int q = lane >> 4;
  const int ln = lane & 15;
  const int col = w * 16 + ln;      // 0..63 within tile

  const unsigned short* bp = W + (size_t)(n0 + col) * 768 + q * 8;
  const unsigned short* ax[4];
  const unsigned short* ah[4];
#pragma unroll
  for (int mb = 0; mb < 4; ++mb) {
    const int brow = m0 + mb * 16 + ln;
    ax[mb] = xb + ((size_t)tx * BB + brow) * DD + q * 8;                  // x_t part, k<256
    ah[mb] = comb + ((size_t)t * BB + brow) * 1024 + dofs + q * 8;        // h_{t-1} part
  }

  f32x4 acc[4];
#pragma unroll
  for (int mb = 0; mb < 4; ++mb) acc[mb] = (f32x4){0.f, 0.f, 0.f, 0.f};

  bf16x8 bcur = ld8(bp);
  bf16x8 acur[4];
#pragma unroll
  for (int mb = 0; mb < 4; ++mb) acur[mb] = ld8(ax[mb]);

  const int NK = 768 / 32;
  for (int ks = 0; ks < NK; ++ks) {
    bf16x8 bnxt = bcur;
    bf16x8 anxt[4] = {acur[0], acur[1], acur[2], acur[3]};
    if (ks + 1 < NK) {
      const int kk = (ks + 1) * 32;
      bnxt = ld8(bp + kk);
#pragma unroll
      for (int mb = 0; mb < 4; ++mb)
        anxt[mb] = (kk < DD) ? ld8(ax[mb] + kk) : ld8(ah[mb] + (kk - DD));
    }
#pragma unroll
    for (int mb = 0; mb < 4; ++mb)
      acc[mb] = __builtin_amdgcn_mfma_f32_16x16x32_bf16(acur[mb], bcur, acc[mb], 0, 0, 0);
    bcur = bnxt;
#pragma unroll
    for (int mb = 0; mb < 4; ++mb) acur[mb] = anxt[mb];
  }

  // accumulators -> LDS (row = mb*16 + q*4 + r, col = col)
#pragma unroll
  for (int mb = 0; mb < 4; ++mb)
#pragma unroll
    for (int r = 0; r < 4; ++r)
      lds[(mb * 16 + q * 4 + r) * 68 + col] = acc[mb][r];
  __syncthreads();

  // fused LSTM cell update: 1024 cells (64 b x 16 j), 4 per thread
#pragma unroll
  for (int r = 0; r < 4; ++r) {
    const int cid = tid + r * 256;
    const int bl = cid & 63;
    const int jl = cid >> 6;
    const int b = m0 + bl;
    const int j = (n0 >> 2) + jl;          // hidden index 0..511
    const float* gp = &lds[bl * 68 + jl * 4];
    const float* bp2 = bias + n0 + jl * 4;
    const float gi = gp[0] + bp2[0];
    const float gf = gp[1] + bp2[1];
    const float gg = gp[2] + bp2[2];
    const float go = gp[3] + bp2[3];
    const float c_old = cbuf[(size_t)b * HH + j];
    const float c_new = sigm(gf) * c_old + sigm(gi) * tanh_f(gg);
    const float h = sigm(go) * tanh_f(c_new);
    cbuf[(size_t)b * HH + j] = c_new;
    comb[((size_t)(t + 1) * BB + b) * 1024 + dofs + j] = f2bf(h);
  }
}

// ---------------------------------------------------------------------------
// One time step of the second-layer LSTM (input 1024, hidden 1024).
// gates[256 x 4096] = [comb_t | h_{t-1}] @ Wpsᵀ  (K = 2048). hs ping-pongs.
// ---------------------------------------------------------------------------
__global__ __launch_bounds__(256) void step3(int t,
    const unsigned short* __restrict__ comb,
    const unsigned short* __restrict__ Wps, const float* __restrict__ bps,
    unsigned short* __restrict__ hs, float* __restrict__ cs) {
  __shared__ float lds[64 * 68];
  const int bi = blockIdx.x;
  const int m0 = (bi >> 6) * 64;
  const int n0 = (bi & 63) * 64;
  const int tid = threadIdx.x;
  const int w = tid >> 6;
  const int lane = tid & 63;
  const int q = lane >> 4;
  const int ln = lane & 15;
  const int col = w * 16 + ln;

  const unsigned short* bp = Wps + (size_t)(n0 + col) * 2048 + q * 8;
  const unsigned short* a1[4];
  const unsigned short* a2[4];
#pragma unroll
  for (int mb = 0; mb < 4; ++mb) {
    const int brow = m0 + mb * 16 + ln;
    a1[mb] = comb + ((size_t)(t + 1) * BB + brow) * 1024 + q * 8;              // combined[t]
    a2[mb] = hs + ((size_t)(t & 1) * BB + brow) * 1024 + q * 8;                // h_{t-1}
  }

  f32x4 acc[4];
#pragma unroll
  for (int mb = 0; mb < 4; ++mb) acc[mb] = (f32x4){0.f, 0.f, 0.f, 0.f};

  bf16x8 bcur = ld8(bp);
  bf16x8 acur[4];
#pragma unroll
  for (int mb = 0; mb < 4; ++mb) acur[mb] = ld8(a1[mb]);

  const int NK = 2048 / 32;
  for (int ks = 0; ks < NK; ++ks) {
    bf16x8 bnxt = bcur;
    bf16x8 anxt[4] = {acur[0], acur[1], acur[2], acur[3]};
    if (ks + 1 < NK) {
      const int kk = (ks + 1) * 32;
      bnxt = ld8(bp + kk);
#pragma unroll
      for (int mb = 0; mb < 4; ++mb)
        anxt[mb] = (kk < 1024) ? ld8(a1[mb] + kk) : ld8(a2[mb] + (kk - 1024));
    }
#pragma unroll
    for (int mb = 0; mb < 4; ++mb)
      acc[mb] = __builtin_amdgcn_mfma_f32_16x16x32_bf16(acur[mb], bcur, acc[mb], 0, 0, 0);
    bcur = bnxt;
#pragma unroll
    for (int mb = 0; mb < 4; ++mb) acur[mb] = anxt[mb];
  }

#pragma unroll
  for (int mb = 0; mb < 4; ++mb)
#pragma unroll
    for (int r = 0; r < 4; ++r)
      lds[(mb * 16 + q * 4 + r) * 68 + col] = acc[mb][r];
  __syncthreads();

#pragma unroll
  for (int r = 0; r < 4; ++r) {
    const int cid = tid + r * 256;
    const int bl = cid & 63;
    const int jl = cid >> 6;
    const int b = m0 + bl;
    const int j = (n0 >> 2) + jl;          // hidden index 0..1023
    const float* gp = &lds[bl * 68 + jl * 4];
    const float* bp2 = bps + n0 + jl * 4;
    const float gi = gp[0] + bp2[0];
    const float gf = gp[1] + bp2[1];
    const float gg = gp[2] + bp2[2];
    const float go = gp[3] + bp2[3];
    const float c_old = cs[(size_t)b * 1024 + j];
    const float c_new = sigm(gf) * c_old + sigm(gi) * tanh_f(gg);
    const float h = sigm(go) * tanh_f(c_new);
    cs[(size_t)b * 1024 + j] = c_new;
    hs[((size_t)((t + 1) & 1) * BB + b) * 1024 + j] = f2bf(h);
  }
}

// ---------------------------------------------------------------------------
// out[b][l] = sigmoid(h_final[b] . Wl[l] + bl[l]);  h_final = hs slot (T&1)=0
// ---------------------------------------------------------------------------
__global__ __launch_bounds__(256) void classifier(const unsigned short* __restrict__ hs,
                                                  const float* __restrict__ Wl,
                                                  const float* __restrict__ bl,
                                                  float* __restrict__ out) {
  const int b = blockIdx.x;
  const int tid = threadIdx.x;
  const unsigned short* hb = hs + (size_t)b * 1024;  // slot 0 (T even)
  float s0 = 0.f, s1 = 0.f;
#pragma unroll
  for (int kk = 0; kk < 4; ++kk) {
    const int k = tid * 4 + kk;
    const float hv = bf2f(hb[k]);
    s0 += hv * Wl[k];
    s1 += hv * Wl[1024 + k];
  }
  for (int off = 32; off > 0; off >>= 1) {
    s0 += __shfl_down(s0, off);
    s1 += __shfl_down(s1, off);
  }
  __shared__ float red[8];
  const int w = tid >> 6;
  if ((tid & 63) == 0) { red[w * 2] = s0; red[w * 2 + 1] = s1; }
  __syncthreads();
  if (tid == 0) {
    const float l0 = red[0] + red[2] + red[4] + red[6] + bl[0];
    const float l1 = red[1] + red[3] + red[5] + red[7] + bl[1];
    out[b * 2 + 0] = sigm(l0);
    out[b * 2 + 1] = sigm(l1);
  }
}

// ---------------------------------------------------------------------------
extern "C" void kernel_launch(void* const* d_in, const int* in_sizes, int n_in,
                              void* d_out, int out_size, void* d_ws, size_t ws_size,
                              hipStream_t stream) {
  const float* x     = (const float*)d_in[0];
  const float* Wf_ih = (const float*)d_in[1];
  const float* Wf_hh = (const float*)d_in[2];
  const float* bf_   = (const float*)d_in[3];
  const float* Wb_ih = (const float*)d_in[4];
  const float* Wb_hh = (const float*)d_in[5];
  const float* bb_   = (const float*)d_in[6];
  const float* Ws_ih = (const float*)d_in[7];
  const float* Ws_hh = (const float*)d_in[8];
  const float* bs_   = (const float*)d_in[9];
  const float* Wl    = (const float*)d_in[10];
  const float* bl    = (const float*)d_in[11];
  float* out = (float*)d_out;

  char* ws = (char*)d_ws;
  size_t off = 0;
  auto take = [&](size_t bytes) -> void* {
    void* p = ws + off;
    off += (bytes + 255) & ~(size_t)255;
    return p;
  };
  unsigned short* xb   = (unsigned short*)take((size_t)BB * TT * DD * 2);       // 16 MB
  unsigned short* Wpf  = (unsigned short*)take((size_t)2048 * 768 * 2);         // 3 MB
  unsigned short* Wpb  = (unsigned short*)take((size_t)2048 * 768 * 2);         // 3 MB
  unsigned short* Wps  = (unsigned short*)take((size_t)4096 * 2048 * 2);        // 16 MB
  float* bpf = (float*)take(2048 * 4);
  float* bpb = (float*)take(2048 * 4);
  float* bps = (float*)take(4096 * 4);
  unsigned short* comb = (unsigned short*)take((size_t)(TT + 1) * BB * 1024 * 2); // 67.6 MB
  unsigned short* hs   = (unsigned short*)take((size_t)2 * BB * 1024 * 2);      // 1 MB
  float* cf = (float*)take((size_t)BB * HH * 4);
  float* cb = (float*)take((size_t)BB * HH * 4);
  float* cs = (float*)take((size_t)BB * 1024 * 4);
  // total ~110.7 MB

  prep<<<2048, 256, 0, stream>>>(x, Wf_ih, Wf_hh, bf_, Wb_ih, Wb_hh, bb_,
                                 Ws_ih, Ws_hh, bs_, xb, Wpf, Wpb, Wps,
                                 bpf, bpb, bps, comb, hs, cf, cb, cs);
  for (int t = 0; t < TT; ++t)
    step_fb<<<256, 256, 0, stream>>>(t, xb, Wpf, Wpb, bpf, bpb, comb, cf, cb);
  for (int t = 0; t < TT; ++t)
    step3<<<256, 256, 0, stream>>>(t, comb, Wps, bps, hs, cs);
  classifier<<<256, 256, 0, stream>>>(hs, Wl, bl, out);
}